// Round 2
// baseline (426.627 us; speedup 1.0000x reference)
//
#include <hip/hip_runtime.h>
#include <hip/hip_fp16.h>

typedef _Float16 half8 __attribute__((ext_vector_type(8)));
typedef _Float16 half4v __attribute__((ext_vector_type(4)));
typedef float float4v __attribute__((ext_vector_type(4)));
typedef int int4a __attribute__((ext_vector_type(4), aligned(4)));
typedef int int2v __attribute__((ext_vector_type(2)));
typedef int int4v __attribute__((ext_vector_type(4)));

#define BLOCK 256
#define ROWS_PER_BLOCK 64
// LDS row pitch in halfs: 96 data + 8 pad -> 208 B rows (16B-aligned for b128).
#define ROWPITCH 104

// Pre-converted f16 weight fragments, laid out so each lane's bfrag[s][t] is a
// contiguous 16B: wh[(s*2+t)*512 + lane*8 + j] = w_s[(t*16+(lane&15))*32 + (lane>>4)*8 + j]
__device__ _Float16 g_wh[6 * 512];

__device__ __forceinline__ void prep_weights_dev(const float* __restrict__ w0,
                                                 const float* __restrict__ w1,
                                                 const float* __restrict__ w2,
                                                 int tid) {
    const int lane = tid & 63;
    for (int st = tid >> 6; st < 6; st += 4) {
        const int s = st >> 1, tt = st & 1;
        const float* w = (s == 0) ? w0 : (s == 1) ? w1 : w2;
        const int o = tt * 16 + (lane & 15);
        const int k = (lane >> 4) * 8;
        #pragma unroll
        for (int j = 0; j < 8; ++j)
            g_wh[st * 512 + lane * 8 + j] = (_Float16)w[o * 32 + k + j];
    }
}

__global__ void prep_weights(const float* __restrict__ w0,
                             const float* __restrict__ w1,
                             const float* __restrict__ w2) {
    prep_weights_dev(w0, w1, w2, (int)threadIdx.x);
}

// x (f32, N x 32) -> q (int8, N x 32B rows) + qs (u8 log2-quantized per-row scale).
// Scale grid: s = 2^((e8-128)/16), chosen so s >= rowmax/127 (ceil in log space,
// +margin for v_log ulp). Quant and dequant both reconstruct s via exp2f ->
// v_exp_f32, so the grid is bit-identical on both sides.
__global__ __launch_bounds__(256) void quantize_x(const float* __restrict__ x,
                                                  char* __restrict__ q,
                                                  unsigned char* __restrict__ qs,
                                                  const float* __restrict__ w0,
                                                  const float* __restrict__ w1,
                                                  const float* __restrict__ w2,
                                                  int N) {
    if (blockIdx.x == 0) prep_weights_dev(w0, w1, w2, (int)threadIdx.x);
    const int stride = gridDim.x * 256;
    for (int row = blockIdx.x * 256 + (int)threadIdx.x; row < N; row += stride) {
        const float4v* xp = (const float4v*)(x + (long)row * 32);
        float4v v[8];
        #pragma unroll
        for (int k = 0; k < 8; ++k) v[k] = __builtin_nontemporal_load(xp + k);
        float m = 0.f;
        #pragma unroll
        for (int k = 0; k < 8; ++k)
            m = fmaxf(m, fmaxf(fmaxf(fabsf(v[k].x), fabsf(v[k].y)),
                               fmaxf(fabsf(v[k].z), fabsf(v[k].w))));
        int e;
        float inv;
        if (m > 0.f) {
            e = (int)ceilf(16.f * log2f(m * (1.f / 127.f)) + 0.001f);
            e = (e < -127) ? -127 : ((e > 127) ? 127 : e);
            inv = exp2f((float)(-e) * 0.0625f);
        } else {
            e = -127;
            inv = 0.f;
        }
        unsigned int w[8];
        #pragma unroll
        for (int k = 0; k < 8; ++k) {
            int b0 = (int)rintf(v[k].x * inv);
            int b1 = (int)rintf(v[k].y * inv);
            int b2 = (int)rintf(v[k].z * inv);
            int b3 = (int)rintf(v[k].w * inv);
            b0 = b0 > 127 ? 127 : (b0 < -127 ? -127 : b0);
            b1 = b1 > 127 ? 127 : (b1 < -127 ? -127 : b1);
            b2 = b2 > 127 ? 127 : (b2 < -127 ? -127 : b2);
            b3 = b3 > 127 ? 127 : (b3 < -127 ? -127 : b3);
            w[k] = (unsigned)(b0 & 255) | ((unsigned)(b1 & 255) << 8) |
                   ((unsigned)(b2 & 255) << 16) | ((unsigned)(b3 & 255) << 24);
        }
        int4v* qp = (int4v*)(q + (long)row * 32);
        qp[0] = (int4v){(int)w[0], (int)w[1], (int)w[2], (int)w[3]};
        qp[1] = (int4v){(int)w[4], (int)w[5], (int)w[6], (int)w[7]};
        qs[row] = (unsigned char)(e + 128);
    }
}

// ---- int8-gather main kernel: rows are 32 B, 4 lanes x 8 bytes per row ----
__global__ __launch_bounds__(BLOCK) void face_conv_i8(
    const char* __restrict__ q,
    const unsigned char* __restrict__ qs,
    const float* __restrict__ bias,
    const int* __restrict__ fn,
    float* __restrict__ out,
    int N)
{
    // Per-wave private A tiles: 4 waves x 16 rows x 104 halfs = 13312 B
    __shared__ alignas(16) _Float16 A[4][16 * ROWPITCH];
    // Per-wave scale staging: banks (r*9+j)%32 are distinct across 16 rows,
    // 4-lane same-address reads broadcast -> conflict-free.
    __shared__ float S[4][16][9];

    const int tid  = threadIdx.x;
    const int wave = tid >> 6;
    const int lane = tid & 63;
    const int m16  = lane & 15;   // MFMA row
    const int quad = lane >> 4;
    const int r    = lane >> 2;   // gather: row within tile (0..15)
    const int c4   = lane & 3;    // gather: 8-channel chunk (0..3)

    half8 bfrag[3][2];
    #pragma unroll
    for (int s = 0; s < 3; ++s)
        #pragma unroll
        for (int t = 0; t < 2; ++t)
            bfrag[s][t] = *(const half8*)(g_wh + (s * 2 + t) * 512 + lane * 8);
    const float bias0 = bias[m16];
    const float bias1 = bias[16 + m16];

    const int base = blockIdx.x * ROWS_PER_BLOCK + wave * 16;
    _Float16* Aw = A[wave];

    int row = base + r;
    row = (row < N) ? row : (N - 1);
    const int* fr = fn + (long)row * 9;
    const int4a i03 = __builtin_nontemporal_load(reinterpret_cast<const int4a*>(fr));
    const int4a i47 = __builtin_nontemporal_load(reinterpret_cast<const int4a*>(fr + 4));
    const int  i8s  = __builtin_nontemporal_load(fr + 8);
    const int idx[9] = {i03.x, i03.y, i03.z, i03.w, i47.x, i47.y, i47.z, i47.w, i8s};

    // Issue the 9 q-row gathers (8 B/lane) first for max MLP.
    int2v qv[9];
    #pragma unroll
    for (int j = 0; j < 9; ++j) {
        const int id = idx[j];
        const int cl = ((unsigned)id < (unsigned)N) ? id : 0;
        qv[j] = *(const int2v*)(q + ((long)cl << 5) + c4 * 8);
    }

    // Cooperative scale fetch: lane c4 loads j=c4 and j=c4+4; c4==0 also j=8.
    {
        const int j0 = c4, j1 = c4 + 4;
        const int id0 = idx[j0], id1 = idx[j1];
        S[wave][r][j0] = ((unsigned)id0 < (unsigned)N)
            ? exp2f((float)((int)qs[id0] - 128) * 0.0625f) : 0.f;
        S[wave][r][j1] = ((unsigned)id1 < (unsigned)N)
            ? exp2f((float)((int)qs[id1] - 128) * 0.0625f) : 0.f;
        if (c4 == 0) {
            const int id2 = idx[8];
            S[wave][r][8] = ((unsigned)id2 < (unsigned)N)
                ? exp2f((float)((int)qs[id2] - 128) * 0.0625f) : 0.f;
        }
    }
    // Intra-wave LDS RAW: drain DS queue before the reads (no barrier needed).
    asm volatile("s_waitcnt lgkmcnt(0)" ::: "memory");
    float sv[9];
    #pragma unroll
    for (int j = 0; j < 9; ++j) sv[j] = S[wave][r][j];

    // Dequant + combine in f32. j literal in unrolled loop -> selects fold,
    // g arrays stay in registers (no runtime indexing).
    float g0f[8] = {0,0,0,0,0,0,0,0};
    float g1f[8] = {0,0,0,0,0,0,0,0};
    float g2f[8] = {0,0,0,0,0,0,0,0};
    #pragma unroll
    for (int j = 0; j < 9; ++j) {
        const float s = sv[j];
        float* g = (j == 0) ? g0f : ((j & 1) ? g1f : g2f);
        #pragma unroll
        for (int e = 0; e < 2; ++e) {
            const int wrd = qv[j][e];
            #pragma unroll
            for (int b = 0; b < 4; ++b) {
                const int val = (wrd << (24 - 8 * b)) >> 24;  // sign-extend byte b
                g[e * 4 + b] += (float)val * s;
            }
        }
    }

    _Float16* dst = Aw + r * ROWPITCH + c4 * 8;
    half8 h0, h1, h2;
    #pragma unroll
    for (int e = 0; e < 8; ++e) {
        h0[e] = (_Float16)g0f[e];
        h1[e] = (_Float16)g1f[e];
        h2[e] = (_Float16)g2f[e];
    }
    *(half8*)(dst)      = h0;
    *(half8*)(dst + 32) = h1;
    *(half8*)(dst + 64) = h2;

    __syncthreads();

    // ---- Phase B: 6 MFMAs per wave (16 rows x 32 outs, K=96) ----
    float4v acc0 = {0.f, 0.f, 0.f, 0.f}, acc1 = {0.f, 0.f, 0.f, 0.f};
    #pragma unroll
    for (int s = 0; s < 3; ++s) {
        half8 a = *(half8*)(Aw + m16 * ROWPITCH + s * 32 + quad * 8);
        acc0 = __builtin_amdgcn_mfma_f32_16x16x32_f16(a, bfrag[s][0], acc0, 0, 0, 0);
        acc1 = __builtin_amdgcn_mfma_f32_16x16x32_f16(a, bfrag[s][1], acc1, 0, 0, 0);
    }

    // Epilogue: C/D layout col = lane&15, row = quad*4 + i.
    #pragma unroll
    for (int i = 0; i < 4; ++i) {
        const int rr = base + quad * 4 + i;
        if (rr < N) {
            __builtin_nontemporal_store(acc0[i] + bias0, &out[(long)rr * 32 + m16]);
            __builtin_nontemporal_store(acc1[i] + bias1, &out[(long)rr * 32 + 16 + m16]);
        }
    }
}

// ---- Fallback (f32 gather) in case the workspace is too small ----
__global__ __launch_bounds__(BLOCK) void face_conv_kernel(
    const float* __restrict__ x,
    const float* __restrict__ bias,
    const int* __restrict__ fn,
    float* __restrict__ out,
    int N)
{
    __shared__ alignas(16) _Float16 A[4][16 * ROWPITCH];

    const int tid  = threadIdx.x;
    const int wave = tid >> 6;
    const int lane = tid & 63;
    const int m16  = lane & 15;
    const int quad = lane >> 4;
    const int oct  = lane >> 3;
    const int m8   = lane & 7;

    half8 bfrag[3][2];
    #pragma unroll
    for (int s = 0; s < 3; ++s)
        #pragma unroll
        for (int t = 0; t < 2; ++t)
            bfrag[s][t] = *(const half8*)(g_wh + (s * 2 + t) * 512 + lane * 8);
    const float bias0 = bias[m16];
    const float bias1 = bias[16 + m16];

    const int base = blockIdx.x * ROWS_PER_BLOCK + wave * 16;
    _Float16* Aw = A[wave];

    int idx[2][9];
    #pragma unroll
    for (int it = 0; it < 2; ++it) {
        int r = base + it * 8 + oct;
        r = (r < N) ? r : (N - 1);
        const int* fr = fn + (long)r * 9;
        #pragma unroll
        for (int j = 0; j < 9; ++j) idx[it][j] = __builtin_nontemporal_load(fr + j);
    }

    #pragma unroll
    for (int it = 0; it < 2; ++it) {
        float4v v[9];
        #pragma unroll
        for (int j = 0; j < 9; ++j) {
            const int id = idx[it][j];
            if ((unsigned)id < (unsigned)N) {
                v[j] = *(const float4v*)(x + (long)id * 32 + m8 * 4);
            } else {
                v[j] = (float4v){0.f, 0.f, 0.f, 0.f};
            }
        }
        const float4v g0 = v[0];
        const float4v g1 = v[1] + v[3] + v[5] + v[7];
        const float4v g2 = v[2] + v[4] + v[6] + v[8];
        _Float16* dst = Aw + (it * 8 + oct) * ROWPITCH + m8 * 4;
        *(half4v*)(dst)      = (half4v){(_Float16)g0.x, (_Float16)g0.y, (_Float16)g0.z, (_Float16)g0.w};
        *(half4v*)(dst + 32) = (half4v){(_Float16)g1.x, (_Float16)g1.y, (_Float16)g1.z, (_Float16)g1.w};
        *(half4v*)(dst + 64) = (half4v){(_Float16)g2.x, (_Float16)g2.y, (_Float16)g2.z, (_Float16)g2.w};
    }

    __syncthreads();

    float4v acc0 = {0.f, 0.f, 0.f, 0.f}, acc1 = {0.f, 0.f, 0.f, 0.f};
    #pragma unroll
    for (int s = 0; s < 3; ++s) {
        half8 a = *(half8*)(Aw + m16 * ROWPITCH + s * 32 + quad * 8);
        acc0 = __builtin_amdgcn_mfma_f32_16x16x32_f16(a, bfrag[s][0], acc0, 0, 0, 0);
        acc1 = __builtin_amdgcn_mfma_f32_16x16x32_f16(a, bfrag[s][1], acc1, 0, 0, 0);
    }

    #pragma unroll
    for (int i = 0; i < 4; ++i) {
        const int r = base + quad * 4 + i;
        if (r < N) {
            __builtin_nontemporal_store(acc0[i] + bias0, &out[(long)r * 32 + m16]);
            __builtin_nontemporal_store(acc1[i] + bias1, &out[(long)r * 32 + 16 + m16]);
        }
    }
}

extern "C" void kernel_launch(void* const* d_in, const int* in_sizes, int n_in,
                              void* d_out, int out_size, void* d_ws, size_t ws_size,
                              hipStream_t stream) {
    const float* x    = (const float*)d_in[0];
    const float* w0   = (const float*)d_in[1];
    const float* w1   = (const float*)d_in[2];
    const float* w2   = (const float*)d_in[3];
    const float* bias = (const float*)d_in[4];
    const int*   fn   = (const int*)d_in[5];
    float* out = (float*)d_out;

    const int N = in_sizes[0] / 32;
    const int blocks = (N + ROWS_PER_BLOCK - 1) / ROWS_PER_BLOCK;

    const size_t need = (size_t)N * 32 + (size_t)N;  // q rows + u8 scales
    if (d_ws != nullptr && ws_size >= need) {
        char* q = (char*)d_ws;
        unsigned char* qsc = (unsigned char*)d_ws + (size_t)N * 32;
        quantize_x<<<2048, 256, 0, stream>>>(x, q, qsc, w0, w1, w2, N);
        face_conv_i8<<<blocks, BLOCK, 0, stream>>>(q, qsc, bias, fn, out, N);
    } else {
        prep_weights<<<1, 384, 0, stream>>>(w0, w1, w2);
        face_conv_kernel<<<blocks, BLOCK, 0, stream>>>(x, bias, fn, out, N);
    }
}

// Round 4
// 375.882 us; speedup vs baseline: 1.1350x; 1.1350x over previous
//
#include <hip/hip_runtime.h>
#include <hip/hip_fp16.h>

typedef _Float16 half8 __attribute__((ext_vector_type(8)));
typedef _Float16 half4v __attribute__((ext_vector_type(4)));
typedef float float4v __attribute__((ext_vector_type(4)));
typedef int int4a __attribute__((ext_vector_type(4), aligned(4)));

#define BLOCK 256
#define ROWS_PER_BLOCK 64
// LDS row pitch in halfs: 96 data + 8 pad -> 208 B rows (16B-aligned for b128).
#define ROWPITCH 104

// Pre-converted f16 weight fragments, laid out so each lane's bfrag[s][t] is a
// contiguous 16B: wh[(s*2+t)*512 + lane*8 + j] = w_s[(t*16+(lane&15))*32 + (lane>>4)*8 + j]
__device__ _Float16 g_wh[6 * 512];

__global__ void prep_weights(const float* __restrict__ w0,
                             const float* __restrict__ w1,
                             const float* __restrict__ w2) {
    const int t = threadIdx.x;           // 0..383
    const int st = t >> 6;               // s*2+tt, 0..5
    const int lane = t & 63;
    const int s = st >> 1, tt = st & 1;
    const float* w = (s == 0) ? w0 : (s == 1) ? w1 : w2;
    const int o = tt * 16 + (lane & 15);
    const int k = (lane >> 4) * 8;
    #pragma unroll
    for (int j = 0; j < 8; ++j)
        g_wh[st * 512 + lane * 8 + j] = (_Float16)w[o * 32 + k + j];
}

// Direct f32-gather kernel. Key change vs the 377µs baseline: launch_bounds
// raised to 128 VGPRs (256 threads, min 4 waves/EU) so BOTH 8-row gather
// groups (18 x dwordx4 = 72 VGPRs of payload) stay in flight simultaneously.
// At VGPR=48 the compiler provably serialized the two groups (~9 loads
// outstanding); the i8 experiment showed sustained TCC BW rises with
// per-wave gather concurrency (3.5 -> 3.9 TB/s at equal bytes).
__global__ __launch_bounds__(BLOCK, 4) void face_conv_kernel(
    const float* __restrict__ x,
    const float* __restrict__ bias,
    const int* __restrict__ fn,
    float* __restrict__ out,
    int N)
{
    // Per-wave private A tiles: 4 waves x 16 rows x 104 halfs = 13312 B
    __shared__ alignas(16) _Float16 A[4][16 * ROWPITCH];

    const int tid  = threadIdx.x;
    const int wave = tid >> 6;
    const int lane = tid & 63;
    const int m16  = lane & 15;   // MFMA row
    const int quad = lane >> 4;   // 0..3
    const int oct  = lane >> 3;   // gather: row within 8-row half-tile
    const int m8   = lane & 7;    // gather: float4 chunk within row

    const int base = blockIdx.x * ROWS_PER_BLOCK + wave * 16;
    _Float16* Aw = A[wave];

    // ---- Index loads first (vectorized, NT: fn is single-use streaming) ----
    int idx[2][9];
    #pragma unroll
    for (int it = 0; it < 2; ++it) {
        int r = base + it * 8 + oct;
        r = (r < N) ? r : (N - 1);           // grid covers N exactly; safety clamp
        const int* fr = fn + (long)r * 9;
        const int4a i03 = __builtin_nontemporal_load(reinterpret_cast<const int4a*>(fr));
        const int4a i47 = __builtin_nontemporal_load(reinterpret_cast<const int4a*>(fr + 4));
        const int  i8s  = __builtin_nontemporal_load(fr + 8);
        idx[it][0] = i03.x; idx[it][1] = i03.y; idx[it][2] = i03.z; idx[it][3] = i03.w;
        idx[it][4] = i47.x; idx[it][5] = i47.y; idx[it][6] = i47.z; idx[it][7] = i47.w;
        idx[it][8] = i8s;
    }

    // ---- Issue ALL 18 gathers before any consumption (max MLP) ----
    // Plain loads: x is the reuse stream; we want L2/L3 to cache it.
    float4v v0[9], v1[9];
    #pragma unroll
    for (int j = 0; j < 9; ++j) {
        const int id = idx[0][j];
        if ((unsigned)id < (unsigned)N) {
            v0[j] = *(const float4v*)(x + (long)id * 32 + m8 * 4);
        } else {
            v0[j] = (float4v){0.f, 0.f, 0.f, 0.f};
        }
    }
    #pragma unroll
    for (int j = 0; j < 9; ++j) {
        const int id = idx[1][j];
        if ((unsigned)id < (unsigned)N) {
            v1[j] = *(const float4v*)(x + (long)id * 32 + m8 * 4);
        } else {
            v1[j] = (float4v){0.f, 0.f, 0.f, 0.f};
        }
    }

    // ---- B fragments + bias: issued after the gather burst (L2-hot, short) ----
    half8 bfrag[3][2];
    #pragma unroll
    for (int s = 0; s < 3; ++s)
        #pragma unroll
        for (int t = 0; t < 2; ++t)
            bfrag[s][t] = *(const half8*)(g_wh + (s * 2 + t) * 512 + lane * 8);
    const float bias0 = bias[m16];
    const float bias1 = bias[16 + m16];

    // ---- Combine + convert + LDS store (waits v0 group, v1 stays in flight) ----
    {
        const float4v g0 = v0[0];
        const float4v g1 = v0[1] + v0[3] + v0[5] + v0[7];
        const float4v g2 = v0[2] + v0[4] + v0[6] + v0[8];
        _Float16* dst = Aw + oct * ROWPITCH + m8 * 4;
        *(half4v*)(dst)      = (half4v){(_Float16)g0.x, (_Float16)g0.y, (_Float16)g0.z, (_Float16)g0.w};
        *(half4v*)(dst + 32) = (half4v){(_Float16)g1.x, (_Float16)g1.y, (_Float16)g1.z, (_Float16)g1.w};
        *(half4v*)(dst + 64) = (half4v){(_Float16)g2.x, (_Float16)g2.y, (_Float16)g2.z, (_Float16)g2.w};
    }
    {
        const float4v g0 = v1[0];
        const float4v g1 = v1[1] + v1[3] + v1[5] + v1[7];
        const float4v g2 = v1[2] + v1[4] + v1[6] + v1[8];
        _Float16* dst = Aw + (8 + oct) * ROWPITCH + m8 * 4;
        *(half4v*)(dst)      = (half4v){(_Float16)g0.x, (_Float16)g0.y, (_Float16)g0.z, (_Float16)g0.w};
        *(half4v*)(dst + 32) = (half4v){(_Float16)g1.x, (_Float16)g1.y, (_Float16)g1.z, (_Float16)g1.w};
        *(half4v*)(dst + 64) = (half4v){(_Float16)g2.x, (_Float16)g2.y, (_Float16)g2.z, (_Float16)g2.w};
    }

    __syncthreads();

    // ---- Phase B: 6 MFMAs per wave (16 rows x 32 outs, K=96) ----
    float4v acc0 = {0.f, 0.f, 0.f, 0.f}, acc1 = {0.f, 0.f, 0.f, 0.f};
    #pragma unroll
    for (int s = 0; s < 3; ++s) {
        half8 a = *(half8*)(Aw + m16 * ROWPITCH + s * 32 + quad * 8);
        acc0 = __builtin_amdgcn_mfma_f32_16x16x32_f16(a, bfrag[s][0], acc0, 0, 0, 0);
        acc1 = __builtin_amdgcn_mfma_f32_16x16x32_f16(a, bfrag[s][1], acc1, 0, 0, 0);
    }

    // Epilogue: C/D layout col = lane&15, row = quad*4 + i. Non-temporal stores
    // keep `out` from thrashing the caches the gathers need.
    #pragma unroll
    for (int i = 0; i < 4; ++i) {
        const int r = base + quad * 4 + i;
        if (r < N) {
            __builtin_nontemporal_store(acc0[i] + bias0, &out[(long)r * 32 + m16]);
            __builtin_nontemporal_store(acc1[i] + bias1, &out[(long)r * 32 + 16 + m16]);
        }
    }
}

extern "C" void kernel_launch(void* const* d_in, const int* in_sizes, int n_in,
                              void* d_out, int out_size, void* d_ws, size_t ws_size,
                              hipStream_t stream) {
    const float* x    = (const float*)d_in[0];
    const float* w0   = (const float*)d_in[1];
    const float* w1   = (const float*)d_in[2];
    const float* w2   = (const float*)d_in[3];
    const float* bias = (const float*)d_in[4];
    const int*   fn   = (const int*)d_in[5];
    float* out = (float*)d_out;

    const int N = in_sizes[0] / 32;
    const int blocks = (N + ROWS_PER_BLOCK - 1) / ROWS_PER_BLOCK;

    prep_weights<<<1, 384, 0, stream>>>(w0, w1, w2);
    face_conv_kernel<<<blocks, BLOCK, 0, stream>>>(x, bias, fn, out, N);
}

// Round 5
// 375.686 us; speedup vs baseline: 1.1356x; 1.0005x over previous
//
#include <hip/hip_runtime.h>
#include <hip/hip_fp16.h>

typedef _Float16 half8 __attribute__((ext_vector_type(8)));
typedef _Float16 half4v __attribute__((ext_vector_type(4)));
typedef float float4v __attribute__((ext_vector_type(4)));
typedef int int4a __attribute__((ext_vector_type(4), aligned(4)));

#define BLOCK 256
#define ROWS_PER_BLOCK 64
// LDS row pitch in halfs: 96 data + 8 pad -> 208 B rows (16B-aligned for b128).
#define ROWPITCH 104

// Pre-converted f16 weight fragments, laid out so each lane's bfrag[s][t] is a
// contiguous 16B: wh[(s*2+t)*512 + lane*8 + j] = w_s[(t*16+(lane&15))*32 + (lane>>4)*8 + j]
__device__ _Float16 g_wh[6 * 512];

__global__ void prep_weights(const float* __restrict__ w0,
                             const float* __restrict__ w1,
                             const float* __restrict__ w2) {
    const int t = threadIdx.x;           // 0..383
    const int st = t >> 6;               // s*2+tt, 0..5
    const int lane = t & 63;
    const int s = st >> 1, tt = st & 1;
    const float* w = (s == 0) ? w0 : (s == 1) ? w1 : w2;
    const int o = tt * 16 + (lane & 15);
    const int k = (lane >> 4) * 8;
    #pragma unroll
    for (int j = 0; j < 8; ++j)
        g_wh[st * 512 + lane * 8 + j] = (_Float16)w[o * 32 + k + j];
}

// f32-gather kernel with FORCED gather concurrency.
// Round-4 lesson: launch_bounds alone doesn't help — the backend scheduler
// sinks loads to their consumers to minimize VGPR pressure (VGPR stayed 48,
// ~9 gathers in flight). This version pins the schedule: all 18 row-gathers
// are issued unconditionally (clamped addresses, validity applied later via
// cndmask selects, NOT exec-masked branches), then sched_barrier(0) prevents
// any sinking. vmcnt retires in order, so the v0-group combine waits only on
// the first 9 loads while the v1 group + bfrag loads remain in flight.
__global__ __launch_bounds__(BLOCK, 4) void face_conv_kernel(
    const float* __restrict__ x,
    const float* __restrict__ bias,
    const int* __restrict__ fn,
    float* __restrict__ out,
    int N)
{
    // Per-wave private A tiles: 4 waves x 16 rows x 104 halfs = 13312 B
    __shared__ alignas(16) _Float16 A[4][16 * ROWPITCH];

    const int tid  = threadIdx.x;
    const int wave = tid >> 6;
    const int lane = tid & 63;
    const int m16  = lane & 15;   // MFMA row
    const int quad = lane >> 4;   // 0..3
    const int oct  = lane >> 3;   // gather: row within 8-row half-tile
    const int m8   = lane & 7;    // gather: float4 chunk within row

    const int base = blockIdx.x * ROWS_PER_BLOCK + wave * 16;
    _Float16* Aw = A[wave];

    // ---- Index loads first (vectorized, NT: fn is single-use streaming) ----
    int idx[2][9];
    #pragma unroll
    for (int it = 0; it < 2; ++it) {
        int r = base + it * 8 + oct;
        r = (r < N) ? r : (N - 1);           // grid covers N exactly; safety clamp
        const int* fr = fn + (long)r * 9;
        const int4a i03 = __builtin_nontemporal_load(reinterpret_cast<const int4a*>(fr));
        const int4a i47 = __builtin_nontemporal_load(reinterpret_cast<const int4a*>(fr + 4));
        const int  i8s  = __builtin_nontemporal_load(fr + 8);
        idx[it][0] = i03.x; idx[it][1] = i03.y; idx[it][2] = i03.z; idx[it][3] = i03.w;
        idx[it][4] = i47.x; idx[it][5] = i47.y; idx[it][6] = i47.z; idx[it][7] = i47.w;
        idx[it][8] = i8s;
    }

    // ---- Issue ALL 18 gathers unconditionally (clamped addresses) ----
    float4v v0[9], v1[9];
    #pragma unroll
    for (int j = 0; j < 9; ++j) {
        const unsigned id = (unsigned)idx[0][j];
        const int cl = (id < (unsigned)N) ? (int)id : 0;
        v0[j] = *(const float4v*)(x + (long)cl * 32 + m8 * 4);
    }
    #pragma unroll
    for (int j = 0; j < 9; ++j) {
        const unsigned id = (unsigned)idx[1][j];
        const int cl = (id < (unsigned)N) ? (int)id : 0;
        v1[j] = *(const float4v*)(x + (long)cl * 32 + m8 * 4);
    }

    // ---- B fragments + bias: issued last (L2-hot, consumed after barrier) ----
    half8 bfrag[3][2];
    #pragma unroll
    for (int s = 0; s < 3; ++s)
        #pragma unroll
        for (int t = 0; t < 2; ++t)
            bfrag[s][t] = *(const half8*)(g_wh + (s * 2 + t) * 512 + lane * 8);
    const float bias0 = bias[m16];
    const float bias1 = bias[16 + m16];

    // Pin the schedule: nothing (especially the gathers above) may be sunk
    // below this point, and no consumer may be hoisted above it.
    __builtin_amdgcn_sched_barrier(0);

    const float4v z = {0.f, 0.f, 0.f, 0.f};

    // ---- Combine v0 (waits vmcnt for first 9 loads only) + LDS store ----
    {
        float4v w[9];
        #pragma unroll
        for (int j = 0; j < 9; ++j)
            w[j] = ((unsigned)idx[0][j] < (unsigned)N) ? v0[j] : z;
        const float4v g0 = w[0];
        const float4v g1 = w[1] + w[3] + w[5] + w[7];
        const float4v g2 = w[2] + w[4] + w[6] + w[8];
        _Float16* dst = Aw + oct * ROWPITCH + m8 * 4;
        *(half4v*)(dst)      = (half4v){(_Float16)g0.x, (_Float16)g0.y, (_Float16)g0.z, (_Float16)g0.w};
        *(half4v*)(dst + 32) = (half4v){(_Float16)g1.x, (_Float16)g1.y, (_Float16)g1.z, (_Float16)g1.w};
        *(half4v*)(dst + 64) = (half4v){(_Float16)g2.x, (_Float16)g2.y, (_Float16)g2.z, (_Float16)g2.w};
    }
    // ---- Combine v1 + LDS store ----
    {
        float4v w[9];
        #pragma unroll
        for (int j = 0; j < 9; ++j)
            w[j] = ((unsigned)idx[1][j] < (unsigned)N) ? v1[j] : z;
        const float4v g0 = w[0];
        const float4v g1 = w[1] + w[3] + w[5] + w[7];
        const float4v g2 = w[2] + w[4] + w[6] + w[8];
        _Float16* dst = Aw + (8 + oct) * ROWPITCH + m8 * 4;
        *(half4v*)(dst)      = (half4v){(_Float16)g0.x, (_Float16)g0.y, (_Float16)g0.z, (_Float16)g0.w};
        *(half4v*)(dst + 32) = (half4v){(_Float16)g1.x, (_Float16)g1.y, (_Float16)g1.z, (_Float16)g1.w};
        *(half4v*)(dst + 64) = (half4v){(_Float16)g2.x, (_Float16)g2.y, (_Float16)g2.z, (_Float16)g2.w};
    }

    __syncthreads();

    // ---- Phase B: 6 MFMAs per wave (16 rows x 32 outs, K=96) ----
    float4v acc0 = {0.f, 0.f, 0.f, 0.f}, acc1 = {0.f, 0.f, 0.f, 0.f};
    #pragma unroll
    for (int s = 0; s < 3; ++s) {
        half8 a = *(half8*)(Aw + m16 * ROWPITCH + s * 32 + quad * 8);
        acc0 = __builtin_amdgcn_mfma_f32_16x16x32_f16(a, bfrag[s][0], acc0, 0, 0, 0);
        acc1 = __builtin_amdgcn_mfma_f32_16x16x32_f16(a, bfrag[s][1], acc1, 0, 0, 0);
    }

    // Epilogue: C/D layout col = lane&15, row = quad*4 + i. Non-temporal stores
    // keep `out` from thrashing the caches the gathers need.
    #pragma unroll
    for (int i = 0; i < 4; ++i) {
        const int r = base + quad * 4 + i;
        if (r < N) {
            __builtin_nontemporal_store(acc0[i] + bias0, &out[(long)r * 32 + m16]);
            __builtin_nontemporal_store(acc1[i] + bias1, &out[(long)r * 32 + 16 + m16]);
        }
    }
}

extern "C" void kernel_launch(void* const* d_in, const int* in_sizes, int n_in,
                              void* d_out, int out_size, void* d_ws, size_t ws_size,
                              hipStream_t stream) {
    const float* x    = (const float*)d_in[0];
    const float* w0   = (const float*)d_in[1];
    const float* w1   = (const float*)d_in[2];
    const float* w2   = (const float*)d_in[3];
    const float* bias = (const float*)d_in[4];
    const int*   fn   = (const int*)d_in[5];
    float* out = (float*)d_out;

    const int N = in_sizes[0] / 32;
    const int blocks = (N + ROWS_PER_BLOCK - 1) / ROWS_PER_BLOCK;

    prep_weights<<<1, 384, 0, stream>>>(w0, w1, w2);
    face_conv_kernel<<<blocks, BLOCK, 0, stream>>>(x, bias, fn, out, N);
}

// Round 6
// 374.779 us; speedup vs baseline: 1.1383x; 1.0024x over previous
//
#include <hip/hip_runtime.h>
#include <hip/hip_fp16.h>

typedef _Float16 half8 __attribute__((ext_vector_type(8)));
typedef _Float16 half4v __attribute__((ext_vector_type(4)));
typedef float float4v __attribute__((ext_vector_type(4)));
typedef int int4a __attribute__((ext_vector_type(4), aligned(4)));

#define BLOCK 256
#define ROWS_PER_BLOCK 64
// LDS row pitch in halfs: 96 data + 8 pad -> 208 B rows (16B-aligned for b128).
#define ROWPITCH 104

// Pre-converted f16 weight fragments, laid out so each lane's bfrag[s][t] is a
// contiguous 16B: wh[(s*2+t)*512 + lane*8 + j] = w_s[(t*16+(lane&15))*32 + (lane>>4)*8 + j]
__device__ _Float16 g_wh[6 * 512];

__global__ void prep_weights(const float* __restrict__ w0,
                             const float* __restrict__ w1,
                             const float* __restrict__ w2) {
    const int t = threadIdx.x;           // 0..383
    const int st = t >> 6;               // s*2+tt, 0..5
    const int lane = t & 63;
    const int s = st >> 1, tt = st & 1;
    const float* w = (s == 0) ? w0 : (s == 1) ? w1 : w2;
    const int o = tt * 16 + (lane & 15);
    const int k = (lane >> 4) * 8;
    #pragma unroll
    for (int j = 0; j < 8; ++j)
        g_wh[st * 512 + lane * 8 + j] = (_Float16)w[o * 32 + k + j];
}

// f32-gather kernel with the i8-round's WIDE lane mapping: 4 lanes per row,
// 16 rows per wave, so EACH gather instruction puts 16 distinct random lines
// in flight (vs 8 with the old oct mapping). The nine half0 loads alone cover
// all 144 lines of the tile — concurrency is baked into instruction shape,
// which the scheduler cannot serialize away (rounds 2-5 showed it undoes any
// source-level hoisting/barrier trick: VGPR stayed 48-56, BW stayed 3.52 TB/s;
// the i8 kernel with this shape sustained 3.93 TB/s at equal bytes).
__global__ __launch_bounds__(BLOCK, 4) void face_conv_kernel(
    const float* __restrict__ x,
    const float* __restrict__ bias,
    const int* __restrict__ fn,
    float* __restrict__ out,
    int N)
{
    // Per-wave private A tiles: 4 waves x 16 rows x 104 halfs = 13312 B
    __shared__ alignas(16) _Float16 A[4][16 * ROWPITCH];

    const int tid  = threadIdx.x;
    const int wave = tid >> 6;
    const int lane = tid & 63;
    const int m16  = lane & 15;   // MFMA row
    const int quad = lane >> 4;   // 0..3
    const int r    = lane >> 2;   // gather: row within 16-row tile (0..15)
    const int c4   = lane & 3;    // gather: 32-B chunk within row (0..3)

    const int base = blockIdx.x * ROWS_PER_BLOCK + wave * 16;
    _Float16* Aw = A[wave];

    // ---- Index loads (vectorized, NT: fn is single-use streaming) ----
    int row = base + r;
    row = (row < N) ? row : (N - 1);         // grid covers N exactly; safety clamp
    const int* fr = fn + (long)row * 9;
    const int4a i03 = __builtin_nontemporal_load(reinterpret_cast<const int4a*>(fr));
    const int4a i47 = __builtin_nontemporal_load(reinterpret_cast<const int4a*>(fr + 4));
    const int  i8s  = __builtin_nontemporal_load(fr + 8);
    const int idx[9] = {i03.x, i03.y, i03.z, i03.w, i47.x, i47.y, i47.z, i47.w, i8s};

    // Clamped per-neighbor base pointers (validity applied post-load via select).
    const float* p[9];
    #pragma unroll
    for (int j = 0; j < 9; ++j) {
        const unsigned id = (unsigned)idx[j];
        const int cl = (id < (unsigned)N) ? (int)id : 0;
        p[j] = x + (long)cl * 32 + c4 * 8;
    }

    // ---- Gather burst: nine half0 loads first (144 distinct lines in flight),
    // then nine half1 loads (same lines; merge in the miss queue / hit L2). ----
    float4v vA[9], vB[9];
    #pragma unroll
    for (int j = 0; j < 9; ++j) vA[j] = *(const float4v*)(p[j]);
    #pragma unroll
    for (int j = 0; j < 9; ++j) vB[j] = *(const float4v*)(p[j] + 4);

    // ---- B fragments + bias: issued last (L2-hot, consumed after barrier) ----
    half8 bfrag[3][2];
    #pragma unroll
    for (int s = 0; s < 3; ++s)
        #pragma unroll
        for (int t = 0; t < 2; ++t)
            bfrag[s][t] = *(const half8*)(g_wh + (s * 2 + t) * 512 + lane * 8);
    const float bias0 = bias[m16];
    const float bias1 = bias[16 + m16];

    __builtin_amdgcn_sched_barrier(0);

    // ---- Mask validity + combine in f32 ----
    const float4v z = {0.f, 0.f, 0.f, 0.f};
    float4v a[9], b[9];
    #pragma unroll
    for (int j = 0; j < 9; ++j) {
        const bool ok = (unsigned)idx[j] < (unsigned)N;
        a[j] = ok ? vA[j] : z;
        b[j] = ok ? vB[j] : z;
    }
    const float4v g0a = a[0];
    const float4v g0b = b[0];
    const float4v g1a = a[1] + a[3] + a[5] + a[7];
    const float4v g1b = b[1] + b[3] + b[5] + b[7];
    const float4v g2a = a[2] + a[4] + a[6] + a[8];
    const float4v g2b = b[2] + b[4] + b[6] + b[8];

    // ---- Convert + LDS store: 16 B per lane per g-group ----
    // Byte addr = r*208 + c4*16 (+64 / +128): banks collide only for r vs r+8
    // (2-way, free on CDNA4).
    _Float16* dst = Aw + r * ROWPITCH + c4 * 8;
    *(half8*)(dst) = (half8){(_Float16)g0a.x, (_Float16)g0a.y, (_Float16)g0a.z, (_Float16)g0a.w,
                             (_Float16)g0b.x, (_Float16)g0b.y, (_Float16)g0b.z, (_Float16)g0b.w};
    *(half8*)(dst + 32) = (half8){(_Float16)g1a.x, (_Float16)g1a.y, (_Float16)g1a.z, (_Float16)g1a.w,
                                  (_Float16)g1b.x, (_Float16)g1b.y, (_Float16)g1b.z, (_Float16)g1b.w};
    *(half8*)(dst + 64) = (half8){(_Float16)g2a.x, (_Float16)g2a.y, (_Float16)g2a.z, (_Float16)g2a.w,
                                  (_Float16)g2b.x, (_Float16)g2b.y, (_Float16)g2b.z, (_Float16)g2b.w};

    __syncthreads();

    // ---- Phase B: 6 MFMAs per wave (16 rows x 32 outs, K=96) ----
    float4v acc0 = {0.f, 0.f, 0.f, 0.f}, acc1 = {0.f, 0.f, 0.f, 0.f};
    #pragma unroll
    for (int s = 0; s < 3; ++s) {
        half8 av = *(half8*)(Aw + m16 * ROWPITCH + s * 32 + quad * 8);
        acc0 = __builtin_amdgcn_mfma_f32_16x16x32_f16(av, bfrag[s][0], acc0, 0, 0, 0);
        acc1 = __builtin_amdgcn_mfma_f32_16x16x32_f16(av, bfrag[s][1], acc1, 0, 0, 0);
    }

    // Epilogue: C/D layout col = lane&15, row = quad*4 + i. Non-temporal stores
    // keep `out` from thrashing the caches the gathers need.
    #pragma unroll
    for (int i = 0; i < 4; ++i) {
        const int rr = base + quad * 4 + i;
        if (rr < N) {
            __builtin_nontemporal_store(acc0[i] + bias0, &out[(long)rr * 32 + m16]);
            __builtin_nontemporal_store(acc1[i] + bias1, &out[(long)rr * 32 + 16 + m16]);
        }
    }
}

extern "C" void kernel_launch(void* const* d_in, const int* in_sizes, int n_in,
                              void* d_out, int out_size, void* d_ws, size_t ws_size,
                              hipStream_t stream) {
    const float* x    = (const float*)d_in[0];
    const float* w0   = (const float*)d_in[1];
    const float* w1   = (const float*)d_in[2];
    const float* w2   = (const float*)d_in[3];
    const float* bias = (const float*)d_in[4];
    const int*   fn   = (const int*)d_in[5];
    float* out = (float*)d_out;

    const int N = in_sizes[0] / 32;
    const int blocks = (N + ROWS_PER_BLOCK - 1) / ROWS_PER_BLOCK;

    prep_weights<<<1, 384, 0, stream>>>(w0, w1, w2);
    face_conv_kernel<<<blocks, BLOCK, 0, stream>>>(x, bias, fn, out, N);
}